// Round 2
// baseline (638.587 us; speedup 1.0000x reference)
//
#include <hip/hip_runtime.h>
#include <math.h>

// GCN1: 2x SplineConv (deg-1 B-spline, KS=5, dim=2) + graclus max-pools + MLP head.
#define NN_F1 32
#define NN_F2 64
#define NN_FH 128
#define NN_NC 10
#define NN_NG 50
#define ACCP 804   // padded A-row stride (f32): 16B-aligned b128 rows, bank-spread

typedef __attribute__((ext_vector_type(8))) short short8v;   // 8 bf16 = 4 VGPRs
typedef __attribute__((ext_vector_type(4))) float f32x4;

// ---------- helpers ----------
__device__ __forceinline__ unsigned fkey(float f) {
    unsigned u = __float_as_uint(f);
    return (u & 0x80000000u) ? ~u : (u | 0x80000000u);
}
__device__ __forceinline__ float funkey(unsigned k) {
    return (k & 0x80000000u) ? __uint_as_float(k & 0x7fffffffu) : __uint_as_float(~k);
}
// pack two floats -> two bf16 (RNE)
__device__ __forceinline__ unsigned bfp2(float a, float b) {
    unsigned ua = __float_as_uint(a), ub = __float_as_uint(b);
    ua += 0x7fffu + ((ua >> 16) & 1u);
    ub += 0x7fffu + ((ub >> 16) & 1u);
    return (ua >> 16) | (ub & 0xffff0000u);
}
__device__ __forceinline__ unsigned short bf1(float a) {
    unsigned u = __float_as_uint(a);
    u += 0x7fffu + ((u >> 16) & 1u);
    return (unsigned short)(u >> 16);
}

// degree-1 open B-spline, KS=5/dim, dim=2. Order matches reference reshape.
__device__ __forceinline__ void spline_basis(float ax, float ay, int wi[4], float bb[4]) {
    float v0 = ax * 4.0f, v1 = ay * 4.0f;
    float l0 = floorf(v0), l1 = floorf(v1);
    float f0 = v0 - l0, f1 = v1 - l1;
    int i0a = (int)l0, i1a = (int)l1;
    int i00 = min(max(i0a, 0), 4), i01 = min(max(i0a + 1, 0), 4);
    int i10 = min(max(i1a, 0), 4), i11 = min(max(i1a + 1, 0), 4);
    float b00 = 1.0f - f0, b01 = f0, b10 = 1.0f - f1, b11 = f1;
    wi[0] = i00 + 5 * i10; bb[0] = b00 * b10;
    wi[1] = i00 + 5 * i11; bb[1] = b00 * b11;
    wi[2] = i01 + 5 * i10; bb[2] = b01 * b10;
    wi[3] = i01 + 5 * i11; bb[3] = b01 * b11;
}

// ---------- K0: CSR indptr via per-node parallel lower_bound ----------
__global__ __launch_bounds__(256) void k_bounds(const int* __restrict__ row, int E,
                                                int* __restrict__ indptr, int N)
{
    int d = blockIdx.x * 256 + threadIdx.x;
    if (d > N) return;
    if (d == N) { indptr[N] = E; return; }
    int l = 0, r = E;
    while (l < r) { int m = (l + r) >> 1; if (row[m] < d) l = m + 1; else r = m; }
    indptr[d] = l;
}

// ---------- K1: conv1, two-phase ----------
// Phase A tap accumulation uses HW LDS float atomics (unsafeAtomicAdd ->
// no-return ds_add_f32): fire-and-forget, no RMW dependency chain across edges.
__global__ __launch_bounds__(128) void k_conv1(
    const float* __restrict__ x, const float* __restrict__ pos,
    const float* __restrict__ eattr, const int* __restrict__ row1,
    const int* __restrict__ indptr,
    const float* __restrict__ W1, const float* __restrict__ root1,
    const float* __restrict__ b1, const int* __restrict__ cluster1,
    unsigned* __restrict__ x2bits, unsigned* __restrict__ cnt1,
    float* __restrict__ possum, unsigned* __restrict__ n2slot, int N)
{
    __shared__ float w1s[25 * NN_F1];
    __shared__ float r1s[NN_F1], b1s[NN_F1];
    __shared__ float g[128][25];          // stride 25 (odd) -> conflict-free phase A
    __shared__ float invdeg[128], xds[128];
    __shared__ int   cls[128];
    __shared__ unsigned blkmax;
    int t = threadIdx.x;
    for (int i = t; i < 25 * NN_F1; i += 128) w1s[i] = W1[i];
    if (t < NN_F1) { r1s[t] = root1[t]; b1s[t] = b1[t]; }
    if (t == 0) blkmax = 0u;

    int d = blockIdx.x * 128 + t;
    float* gr = g[t];
#pragma unroll
    for (int k = 0; k < 25; ++k) gr[k] = 0.f;

    if (d < N) {
        int lo = indptr[d], hi = indptr[d + 1];
        for (int e = lo; e < hi; ++e) {
            int s = row1[e];
            float2 ea = ((const float2*)eattr)[e];
            int wi[4]; float bb[4];
            spline_basis(1.0f - ea.x, 1.0f - ea.y, wi, bb);
            float xv = x[s];
            unsafeAtomicAdd(&gr[wi[0]], bb[0] * xv);   // ds_add_f32 no-rtn
            unsafeAtomicAdd(&gr[wi[1]], bb[1] * xv);
            unsafeAtomicAdd(&gr[wi[2]], bb[2] * xv);
            unsafeAtomicAdd(&gr[wi[3]], bb[3] * xv);
        }
        invdeg[t] = 1.0f / (float)max(hi - lo, 1);
        xds[t] = x[d];
        int c = cluster1[d];
        cls[t] = c;
        atomicAdd(&cnt1[c], 1u);
        unsafeAtomicAdd(&possum[2 * c], pos[2 * d]);
        unsafeAtomicAdd(&possum[2 * c + 1], pos[2 * d + 1]);
        atomicMax(&blkmax, (unsigned)c);
    }
    __syncthreads();
    if (t == 0) atomicMax(n2slot, blkmax);

    // Phase B: 4 groups x 32 lanes; lane o owns output feature o.
    int grp = t >> 5, o = t & 31;
    float wreg[25];
#pragma unroll
    for (int k = 0; k < 25; ++k) wreg[k] = w1s[k * NN_F1 + o];
    float ro = r1s[o], bo = b1s[o];
    int nloc = min(128, N - blockIdx.x * 128);
    for (int i = grp; i < nloc; i += 4) {
        float acc = 0.f;
#pragma unroll
        for (int k = 0; k < 25; ++k) acc += g[i][k] * wreg[k];
        float h = acc * invdeg[i] + xds[i] * ro + bo;
        h = h > 0.f ? h : expm1f(h);
        atomicMax(&x2bits[(size_t)cls[i] * NN_F1 + o], fkey(h));
    }
}

// ---------- K2: finalize x2 -> bf16 (zero empties), pos2 = possum/cnt ----------
__global__ __launch_bounds__(256) void k_fin1(const unsigned* __restrict__ x2b,
                                              const unsigned* __restrict__ cnt1,
                                              unsigned short* __restrict__ x2bf,
                                              float* __restrict__ possum, int N)
{
    int i = blockIdx.x * 256 + threadIdx.x;
    int n = i >> 5, o = i & 31;
    if (n >= N) return;
    unsigned cnt = cnt1[n];
    float v = cnt ? funkey(x2b[i]) : 0.0f;
    x2bf[i] = bf1(v);
    if (o < 2) {
        float p = possum[2 * n + o];
        possum[2 * n + o] = p / (float)max(cnt, 1u);
    }
}

// ---------- K3: global max|cart| over pooled edges (block-reduced, 1 atomic/block) ----------
__global__ __launch_bounds__(256) void k_maxabs(const int* __restrict__ r0,
                                                const int* __restrict__ r1, int E2,
                                                const float* __restrict__ pos2,
                                                unsigned* __restrict__ maxbits)
{
    __shared__ float wmax[4];
    float m = 0.f;
    for (int e = blockIdx.x * 256 + threadIdx.x; e < E2; e += gridDim.x * 256) {
        int a = r0[e], b = r1[e];
        float cx = pos2[2 * a] - pos2[2 * b];
        float cy = pos2[2 * a + 1] - pos2[2 * b + 1];
        m = fmaxf(m, fmaxf(fabsf(cx), fabsf(cy)));
    }
    for (int off = 32; off; off >>= 1) m = fmaxf(m, __shfl_down(m, off));
    if ((threadIdx.x & 63) == 0) wmax[threadIdx.x >> 6] = m;
    __syncthreads();
    if (threadIdx.x == 0) {
        m = fmaxf(fmaxf(wmax[0], wmax[1]), fmaxf(wmax[2], wmax[3]));
        atomicMax(maxbits, __float_as_uint(m));   // all values >= 0: bit-compare ok
    }
}

// ---------- K3b: W2 -> W2T bf16 [64][800]; root2 -> r2T bf16 [64][32] ----------
__global__ __launch_bounds__(256) void k_w2cvt(const float* __restrict__ W2,
                                               const float* __restrict__ root2,
                                               unsigned short* __restrict__ W2T,
                                               unsigned short* __restrict__ r2T)
{
    int i = blockIdx.x * 256 + threadIdx.x;
    if (i < 800 * 64) {
        int k = i >> 6, n = i & 63;
        W2T[n * 800 + k] = bf1(W2[i]);
    } else if (i < 800 * 64 + 64 * 32) {
        int j = i - 800 * 64;
        int o = j >> 5, f = j & 31;
        r2T[o * 32 + f] = bf1(root2[f * 64 + o]);
    }
}

// ---------- K3c: per-edge basis precompute -> 32B records {bb f32x4, s, wj, d} ----------
__global__ __launch_bounds__(256) void k_basis(
    const int* __restrict__ r0, const int* __restrict__ r1, int E2,
    const float* __restrict__ pos2, const unsigned* __restrict__ scal,
    float* __restrict__ rec)
{
    int e = blockIdx.x * 256 + threadIdx.x;
    if (e >= E2) return;
    float denom = 2.0f * __uint_as_float(scal[1]);
    int d = r0[e], s = r1[e];          // true edge is (s -> d): cart = pos2[s] - pos2[d]
    float ax = (pos2[2 * s] - pos2[2 * d]) / denom + 0.5f;
    float ay = (pos2[2 * s + 1] - pos2[2 * d + 1]) / denom + 0.5f;
    int wi[4]; float bb[4];
    spline_basis(ax, ay, wi, bb);
    unsigned wj = (unsigned)wi[0] | ((unsigned)wi[1] << 8)
                | ((unsigned)wi[2] << 16) | ((unsigned)wi[3] << 24);
    float* rp = rec + (size_t)e * 8;
    *(float4*)rp = make_float4(bb[0], bb[1], bb[2], bb[3]);
    ((int*)rp)[4] = s;
    ((unsigned*)rp)[5] = wj;
    ((int*)rp)[6] = d;                 // dst row for block-parallel scatter
}

// ---------- K4: conv2 FUSED scatter + MFMA GEMM + epilogue (no G buffer) ----------
// Block = 16 nodes, 256 threads. Phase 1: block-wide EDGE-PARALLEL scatter over the
// block's contiguous CSR range [indptr2[nb], indptr2[nb+16]); 16 subgroups x 16 lanes,
// lane owns a feature pair; accumulation via HW ds_add_f32 atomics (unsafeAtomicAdd:
// fire-and-forget, no RMW dependency chain, no per-node max-degree lockstep).
// Phase 2: 4 waves x 16-col blocks, K=800 MFMA loop with A-frags read from LDS
// (b128 + RNE bf16 pack), fused epilogue (/deg, +x2@root2 via MFMA, +b2, elu,
// pool2 atomicMax).
__device__ __forceinline__ short8v ld_frag(const unsigned short* p) {
    short8v a;
    ((unsigned long long*)&a)[0] = *(const unsigned long long*)(p);        // k+0..3
    ((unsigned long long*)&a)[1] = *(const unsigned long long*)(p + 16);   // k+16..19
    return a;
}
__device__ __forceinline__ short8v pack_frag(float4 a, float4 b) {
    union { unsigned u[4]; short8v s; } r;
    r.u[0] = bfp2(a.x, a.y); r.u[1] = bfp2(a.z, a.w);
    r.u[2] = bfp2(b.x, b.y); r.u[3] = bfp2(b.z, b.w);
    return r.s;
}
__global__ __launch_bounds__(256) void k_conv2(
    const float* __restrict__ rec, const int* __restrict__ indptr2,
    const unsigned short* __restrict__ x2bf, const unsigned short* __restrict__ W2T,
    const unsigned short* __restrict__ r2T, const float* __restrict__ b2,
    const int* __restrict__ cluster2, unsigned* __restrict__ x3bits,
    const unsigned* __restrict__ scal, int N)
{
    __shared__ float accs[16 * ACCP];
    __shared__ float degl[16];
    int n2 = (int)scal[0] + 1;
    int nb = blockIdx.x * 16;
    if (nb >= n2) return;                 // block-uniform exit (before any barrier)
    int t = threadIdx.x;

    // zero acc (float4) + per-node degrees
    float4* az = (float4*)accs;
    for (int j = t; j < 16 * ACCP / 4; j += 256) az[j] = make_float4(0.f, 0.f, 0.f, 0.f);
    if (t < 16) {
        int d = nb + t;                   // d < N: nb < n2 <= N and grid covers N/16
        degl[t] = (float)max(indptr2[d + 1] - indptr2[d], 1);
    }
    __syncthreads();

    // ---- phase 1: edge-parallel scatter, subgroup g takes edges e0+g, e0+g+16, ... ----
    int g = t >> 4, f2 = (t & 15) << 1;   // subgroup, feature pair f2/f2+1
    int e0 = indptr2[nb];
    int e1 = indptr2[min(nb + 16, N)];
    for (int e = e0 + g; e < e1; e += 16) {
        const float* rp = rec + (size_t)e * 8;
        float4 bb = *(const float4*)rp;                 // broadcast within subgroup
        int s = ((const int*)rp)[4];
        unsigned wj = ((const unsigned*)rp)[5];
        int r = ((const int*)rp)[6] - nb;               // LDS row for this edge's dst
        unsigned xv2 = *(const unsigned*)(x2bf + (size_t)s * 32 + f2);
        float xlo = __uint_as_float(xv2 << 16);
        float xhi = __uint_as_float(xv2 & 0xffff0000u);
        float* acc = accs + r * ACCP + f2;
        float* a0 = acc + ((wj & 31u) << 5);
        float* a1 = acc + (((wj >> 8) & 31u) << 5);
        float* a2 = acc + (((wj >> 16) & 31u) << 5);
        float* a3 = acc + (((wj >> 24) & 31u) << 5);
        unsafeAtomicAdd(a0, bb.x * xlo);  unsafeAtomicAdd(a0 + 1, bb.x * xhi);
        unsafeAtomicAdd(a1, bb.y * xlo);  unsafeAtomicAdd(a1 + 1, bb.y * xhi);
        unsafeAtomicAdd(a2, bb.z * xlo);  unsafeAtomicAdd(a2 + 1, bb.z * xhi);
        unsafeAtomicAdd(a3, bb.w * xlo);  unsafeAtomicAdd(a3 + 1, bb.w * xhi);
    }
    __syncthreads();

    // ---- phase 2: per-wave 16x16 col-block GEMM from LDS + fused epilogue ----
    int w = t >> 6, l = t & 63;
    int lg = l >> 4, lr = l & 15;
    int c0 = w * 16;
    const float* arow = accs + lr * ACCP;
    const unsigned short* pb = W2T + (size_t)(c0 + lr) * 800 + 4 * lg;

    f32x4 s4 = {0.f, 0.f, 0.f, 0.f};
    for (int kk = 0; kk < 800; kk += 32) {
        float4 a0 = *(const float4*)(arow + kk + 4 * lg);
        float4 a1 = *(const float4*)(arow + kk + 16 + 4 * lg);
        short8v af = pack_frag(a0, a1);
        short8v bf = ld_frag(pb + kk);
        s4 = __builtin_amdgcn_mfma_f32_16x16x32_bf16(af, bf, s4, 0, 0, 0);
    }

    int r0g = nb + 4 * lg;
#pragma unroll
    for (int i = 0; i < 4; ++i) {
        int gr = r0g + i;
        float invd = (gr < n2) ? 1.0f / degl[4 * lg + i] : 0.0f;
        s4[i] *= invd;
    }
    int ar2 = nb + lr; if (ar2 > N - 1) ar2 = N - 1;
    short8v a2f = ld_frag(x2bf + (size_t)ar2 * 32 + 4 * lg);
    s4 = __builtin_amdgcn_mfma_f32_16x16x32_bf16(
             a2f, ld_frag(r2T + (size_t)(c0 + lr) * 32 + 4 * lg), s4, 0, 0, 0);

    float bs = b2[c0 + lr];
#pragma unroll
    for (int i = 0; i < 4; ++i) {
        int gr = r0g + i;
        if (gr >= n2) continue;
        float h = s4[i] + bs;
        h = h > 0.f ? h : expm1f(h);
        atomicMax(&x3bits[(size_t)cluster2[gr] * 64 + c0 + lr], fkey(h));
    }
}

// ---------- K6: graph mean-pool numerators/denominators (LDS histogram) ----------
__global__ __launch_bounds__(256) void k_gsum(const unsigned* __restrict__ x3bits,
                                              const int* __restrict__ batch3,
                                              float* __restrict__ sbuf,
                                              unsigned* __restrict__ cbuf, int N)
{
    __shared__ float sl[NN_NG * 64];
    __shared__ unsigned clh[NN_NG];
    int t = threadIdx.x;
    for (int i = t; i < NN_NG * 64; i += 256) sl[i] = 0.f;
    if (t < NN_NG) clh[t] = 0u;
    __syncthreads();
    int o = t & 63, rsub = t >> 6;
    for (int i0 = blockIdx.x * 4; i0 < N; i0 += gridDim.x * 4) {
        int i = i0 + rsub;
        if (i < N) {
            int g = batch3[i];
            if (g < NN_NG) {   // dummy graph id NG is dropped
                float v = funkey(x3bits[(size_t)i * 64 + o]);
                unsafeAtomicAdd(&sl[g * 64 + o], v);
                if (o == 0) atomicAdd(&clh[g], 1u);
            }
        }
    }
    __syncthreads();
    for (int i = t; i < NN_NG * 64; i += 256) unsafeAtomicAdd(&sbuf[i], sl[i]);
    if (t < NN_NG) atomicAdd(&cbuf[t], clh[t]);
}

// ---------- K7: MLP head + log_softmax ----------
__global__ __launch_bounds__(128) void k_head(const float* __restrict__ sbuf,
                                              const unsigned* __restrict__ cbuf,
                                              const float* __restrict__ fc1w,
                                              const float* __restrict__ fc1b,
                                              const float* __restrict__ fc2w,
                                              const float* __restrict__ fc2b,
                                              float* __restrict__ out)
{
    __shared__ float xg[64], hl[NN_FH], ll[NN_NC];
    int g = blockIdx.x, t = threadIdx.x;
    if (t < 64) xg[t] = sbuf[g * 64 + t] / (float)max(cbuf[g], 1u);
    __syncthreads();
    float a = fc1b[t];
    for (int f = 0; f < 64; ++f) a += xg[f] * fc1w[f * NN_FH + t];
    hl[t] = a > 0.f ? a : expm1f(a);
    __syncthreads();
    if (t < NN_NC) {
        float l = fc2b[t];
        for (int h = 0; h < NN_FH; ++h) l += hl[h] * fc2w[h * NN_NC + t];
        ll[t] = l;
    }
    __syncthreads();
    if (t < NN_NC) {
        float m = ll[0];
        for (int j = 1; j < NN_NC; ++j) m = fmaxf(m, ll[j]);
        float sum = 0.f;
        for (int j = 0; j < NN_NC; ++j) sum += expf(ll[j] - m);
        out[g * NN_NC + t] = ll[t] - m - logf(sum);
    }
}

// ---------- launch ----------
extern "C" void kernel_launch(void* const* d_in, const int* in_sizes, int n_in,
                              void* d_out, int out_size, void* d_ws, size_t ws_size,
                              hipStream_t stream)
{
    const float* x        = (const float*)d_in[0];
    const float* pos      = (const float*)d_in[1];
    const float* eattr    = (const float*)d_in[2];
    const int*   ei       = (const int*)d_in[3];
    const int*   cluster1 = (const int*)d_in[4];
    const int*   ei2      = (const int*)d_in[5];
    const int*   cluster2 = (const int*)d_in[6];
    const int*   batch3   = (const int*)d_in[7];
    const float* W1    = (const float*)d_in[9];
    const float* root1 = (const float*)d_in[10];
    const float* b1    = (const float*)d_in[11];
    const float* W2    = (const float*)d_in[12];
    const float* root2 = (const float*)d_in[13];
    const float* b2    = (const float*)d_in[14];
    const float* fc1w  = (const float*)d_in[15];
    const float* fc1b  = (const float*)d_in[16];
    const float* fc2w  = (const float*)d_in[17];
    const float* fc2b  = (const float*)d_in[18];

    const int N  = in_sizes[0];        // x is [N,1]
    const int E  = in_sizes[3] / 2;
    const int E2 = in_sizes[5] / 2;

    char* base = (char*)d_ws;
    size_t off = 0;
    auto alloc = [&](size_t b) { size_t o = off; off += (b + 255) & ~(size_t)255; return o; };
    size_t o_x2b  = alloc((size_t)N * 32 * 4);   // x2bits (atomicMax target)
    size_t o_x3   = alloc((size_t)N * 64 * 4);   // x3bits
    size_t o_cnt1 = alloc((size_t)N * 4);
    size_t o_psum = alloc((size_t)N * 2 * 4);    // possum -> pos2 (in place)
    size_t o_ip1  = alloc((size_t)(N + 1) * 4);
    size_t o_ip2  = alloc((size_t)(N + 1) * 4);
    size_t o_s    = alloc((size_t)NN_NG * 64 * 4);
    size_t o_c    = alloc(64 * 4);
    size_t o_scal = alloc(256);                  // [0]=max cluster1, [1]=maxabs bits
    size_t fixed  = off;                         // memset covers [0, fixed)
    size_t o_x2bf = alloc((size_t)N * 32 * 2);   // x2 bf16 (fully written by fin1)
    size_t o_w2t  = alloc((size_t)64 * 800 * 2); // W2T bf16
    size_t o_r2t  = alloc((size_t)64 * 32 * 2);  // root2T bf16
    size_t o_rec  = alloc((size_t)E2 * 32);      // per-edge basis records
    (void)ws_size;

    unsigned* x2bits = (unsigned*)(base + o_x2b);
    unsigned* x3bits = (unsigned*)(base + o_x3);
    unsigned* cnt1   = (unsigned*)(base + o_cnt1);
    float*    possum = (float*)(base + o_psum);
    int*      ip1    = (int*)(base + o_ip1);
    int*      ip2    = (int*)(base + o_ip2);
    float*    sbuf   = (float*)(base + o_s);
    unsigned* cbuf   = (unsigned*)(base + o_c);
    unsigned* scal   = (unsigned*)(base + o_scal);
    unsigned short* x2bf = (unsigned short*)(base + o_x2bf);
    unsigned short* W2T  = (unsigned short*)(base + o_w2t);
    unsigned short* r2T  = (unsigned short*)(base + o_r2t);
    float*    rec    = (float*)(base + o_rec);

    hipMemsetAsync(d_ws, 0, fixed, stream);

    k_bounds<<<(N + 256) / 256, 256, 0, stream>>>(ei, E, ip1, N);
    k_bounds<<<(N + 256) / 256, 256, 0, stream>>>(ei2, E2, ip2, N);
    k_w2cvt<<<(800 * 64 + 64 * 32 + 255) / 256, 256, 0, stream>>>(W2, root2, W2T, r2T);

    k_conv1<<<(N + 127) / 128, 128, 0, stream>>>(x, pos, eattr, ei + E, ip1,
                                                 W1, root1, b1, cluster1,
                                                 x2bits, cnt1, possum, &scal[0], N);
    k_fin1<<<(N * 32 + 255) / 256, 256, 0, stream>>>(x2bits, cnt1, x2bf, possum, N);

    int mb = (E2 + 255) / 256;
    if (mb > 256) mb = 256;
    const float* pos2 = (const float*)(base + o_psum);
    k_maxabs<<<mb, 256, 0, stream>>>(ei2, ei2 + E2, E2, pos2, &scal[1]);
    k_basis<<<(E2 + 255) / 256, 256, 0, stream>>>(ei2, ei2 + E2, E2, pos2,
                                                  scal, rec);

    k_conv2<<<(N + 15) / 16, 256, 0, stream>>>(rec, ip2, x2bf, W2T, r2T, b2,
                                               cluster2, x3bits, scal, N);

    k_gsum<<<256, 256, 0, stream>>>(x3bits, batch3, sbuf, cbuf, N);
    k_head<<<NN_NG, 128, 0, stream>>>(sbuf, cbuf, fc1w, fc1b, fc2w, fc2b, (float*)d_out);
}

// Round 3
// 263.199 us; speedup vs baseline: 2.4263x; 2.4263x over previous
//
#include <hip/hip_runtime.h>
#include <math.h>

// GCN1: 2x SplineConv (deg-1 B-spline, KS=5, dim=2) + graclus max-pools + MLP head.
#define NN_F1 32
#define NN_F2 64
#define NN_FH 128
#define NN_NC 10
#define NN_NG 50
#define ACCP 804   // padded A-row stride (f32): 16B-aligned b128 rows, bank-spread

typedef __attribute__((ext_vector_type(8))) short short8v;   // 8 bf16 = 4 VGPRs
typedef __attribute__((ext_vector_type(4))) float f32x4;

// ---------- helpers ----------
__device__ __forceinline__ unsigned fkey(float f) {
    unsigned u = __float_as_uint(f);
    return (u & 0x80000000u) ? ~u : (u | 0x80000000u);
}
__device__ __forceinline__ float funkey(unsigned k) {
    return (k & 0x80000000u) ? __uint_as_float(k & 0x7fffffffu) : __uint_as_float(~k);
}
// pack two floats -> two bf16 (RNE)
__device__ __forceinline__ unsigned bfp2(float a, float b) {
    unsigned ua = __float_as_uint(a), ub = __float_as_uint(b);
    ua += 0x7fffu + ((ua >> 16) & 1u);
    ub += 0x7fffu + ((ub >> 16) & 1u);
    return (ua >> 16) | (ub & 0xffff0000u);
}
__device__ __forceinline__ unsigned short bf1(float a) {
    unsigned u = __float_as_uint(a);
    u += 0x7fffu + ((u >> 16) & 1u);
    return (unsigned short)(u >> 16);
}

// degree-1 open B-spline, KS=5/dim, dim=2 — SEPARABLE form.
// ix = {i00,i01,i10,i11}, bv = {b00,b01,b10,b11}; flat tap = ix_x + 5*ix_y.
__device__ __forceinline__ void spline_sep(float ax, float ay, int ix[4], float bv[4]) {
    float v0 = ax * 4.0f, v1 = ay * 4.0f;
    float l0 = floorf(v0), l1 = floorf(v1);
    float f0 = v0 - l0, f1 = v1 - l1;
    int i0a = (int)l0, i1a = (int)l1;
    ix[0] = min(max(i0a, 0), 4);     ix[1] = min(max(i0a + 1, 0), 4);
    ix[2] = min(max(i1a, 0), 4);     ix[3] = min(max(i1a + 1, 0), 4);
    bv[0] = 1.0f - f0; bv[1] = f0; bv[2] = 1.0f - f1; bv[3] = f1;
}

// ---------- K0: CSR indptr via per-node parallel lower_bound ----------
__global__ __launch_bounds__(256) void k_bounds(const int* __restrict__ row, int E,
                                                int* __restrict__ indptr, int N)
{
    int d = blockIdx.x * 256 + threadIdx.x;
    if (d > N) return;
    if (d == N) { indptr[N] = E; return; }
    int l = 0, r = E;
    while (l < r) { int m = (l + r) >> 1; if (row[m] < d) l = m + 1; else r = m; }
    indptr[d] = l;
}

// ---------- K1: conv1, two-phase ----------
// Phase A: per-thread REGISTER accumulation of the 25-tap row via predicated
// selects (no LDS RMW chain, no atomics). One dump to LDS at the end.
__global__ __launch_bounds__(128) void k_conv1(
    const float* __restrict__ x, const float* __restrict__ pos,
    const float* __restrict__ eattr, const int* __restrict__ row1,
    const int* __restrict__ indptr,
    const float* __restrict__ W1, const float* __restrict__ root1,
    const float* __restrict__ b1, const int* __restrict__ cluster1,
    unsigned* __restrict__ x2bits, unsigned* __restrict__ cnt1,
    float* __restrict__ possum, unsigned* __restrict__ n2slot, int N)
{
    __shared__ float w1s[25 * NN_F1];
    __shared__ float r1s[NN_F1], b1s[NN_F1];
    __shared__ float g[128][25];          // stride 25 (odd) -> conflict-free
    __shared__ float invdeg[128], xds[128];
    __shared__ int   cls[128];
    __shared__ unsigned blkmax;
    int t = threadIdx.x;
    for (int i = t; i < 25 * NN_F1; i += 128) w1s[i] = W1[i];
    if (t < NN_F1) { r1s[t] = root1[t]; b1s[t] = b1[t]; }
    if (t == 0) blkmax = 0u;

    int d = blockIdx.x * 128 + t;
    float acc[25];
#pragma unroll
    for (int k = 0; k < 25; ++k) acc[k] = 0.f;

    if (d < N) {
        int lo = indptr[d], hi = indptr[d + 1];
        for (int e = lo; e < hi; ++e) {
            int s = row1[e];
            float2 ea = ((const float2*)eattr)[e];
            int ix[4]; float bv[4];
            spline_sep(1.0f - ea.x, 1.0f - ea.y, ix, bv);
            float xv = x[s];
            float cx[5], cy[5];
#pragma unroll
            for (int i = 0; i < 5; ++i) {
                cx[i] = (i == ix[0] ? bv[0] : 0.f) + (i == ix[1] ? bv[1] : 0.f);
                cy[i] = (i == ix[2] ? bv[2] : 0.f) + (i == ix[3] ? bv[3] : 0.f);
            }
#pragma unroll
            for (int ky = 0; ky < 5; ++ky) {
                float m = cy[ky] * xv;
#pragma unroll
                for (int kx = 0; kx < 5; ++kx) acc[5 * ky + kx] += cx[kx] * m;
            }
        }
        invdeg[t] = 1.0f / (float)max(hi - lo, 1);
        xds[t] = x[d];
        int c = cluster1[d];
        cls[t] = c;
        atomicAdd(&cnt1[c], 1u);
        atomicAdd(&possum[2 * c], pos[2 * d]);
        atomicAdd(&possum[2 * c + 1], pos[2 * d + 1]);
        atomicMax(&blkmax, (unsigned)c);
    }
#pragma unroll
    for (int k = 0; k < 25; ++k) g[t][k] = acc[k];   // one-time dump
    __syncthreads();
    if (t == 0) atomicMax(n2slot, blkmax);

    // Phase B: 4 groups x 32 lanes; lane o owns output feature o.
    int grp = t >> 5, o = t & 31;
    float wreg[25];
#pragma unroll
    for (int k = 0; k < 25; ++k) wreg[k] = w1s[k * NN_F1 + o];
    float ro = r1s[o], bo = b1s[o];
    int nloc = min(128, N - blockIdx.x * 128);
    for (int i = grp; i < nloc; i += 4) {
        float a = 0.f;
#pragma unroll
        for (int k = 0; k < 25; ++k) a += g[i][k] * wreg[k];
        float h = a * invdeg[i] + xds[i] * ro + bo;
        h = h > 0.f ? h : expm1f(h);
        atomicMax(&x2bits[(size_t)cls[i] * NN_F1 + o], fkey(h));
    }
}

// ---------- K2: finalize x2 -> bf16 (zero empties), pos2 = possum/cnt ----------
__global__ __launch_bounds__(256) void k_fin1(const unsigned* __restrict__ x2b,
                                              const unsigned* __restrict__ cnt1,
                                              unsigned short* __restrict__ x2bf,
                                              float* __restrict__ possum, int N)
{
    int i = blockIdx.x * 256 + threadIdx.x;
    int n = i >> 5, o = i & 31;
    if (n >= N) return;
    unsigned cnt = cnt1[n];
    float v = cnt ? funkey(x2b[i]) : 0.0f;
    x2bf[i] = bf1(v);
    if (o < 2) {
        float p = possum[2 * n + o];
        possum[2 * n + o] = p / (float)max(cnt, 1u);
    }
}

// ---------- K3: global max|cart| over pooled edges (block-reduced, 1 atomic/block) ----------
__global__ __launch_bounds__(256) void k_maxabs(const int* __restrict__ r0,
                                                const int* __restrict__ r1, int E2,
                                                const float* __restrict__ pos2,
                                                unsigned* __restrict__ maxbits)
{
    __shared__ float wmax[4];
    float m = 0.f;
    for (int e = blockIdx.x * 256 + threadIdx.x; e < E2; e += gridDim.x * 256) {
        int a = r0[e], b = r1[e];
        float cx = pos2[2 * a] - pos2[2 * b];
        float cy = pos2[2 * a + 1] - pos2[2 * b + 1];
        m = fmaxf(m, fmaxf(fabsf(cx), fabsf(cy)));
    }
    for (int off = 32; off; off >>= 1) m = fmaxf(m, __shfl_down(m, off));
    if ((threadIdx.x & 63) == 0) wmax[threadIdx.x >> 6] = m;
    __syncthreads();
    if (threadIdx.x == 0) {
        m = fmaxf(fmaxf(wmax[0], wmax[1]), fmaxf(wmax[2], wmax[3]));
        atomicMax(maxbits, __float_as_uint(m));   // all values >= 0: bit-compare ok
    }
}

// ---------- K3b: W2 -> W2T bf16 [64][800]; root2 -> r2T bf16 [64][32] ----------
__global__ __launch_bounds__(256) void k_w2cvt(const float* __restrict__ W2,
                                               const float* __restrict__ root2,
                                               unsigned short* __restrict__ W2T,
                                               unsigned short* __restrict__ r2T)
{
    int i = blockIdx.x * 256 + threadIdx.x;
    if (i < 800 * 64) {
        int k = i >> 6, n = i & 63;
        W2T[n * 800 + k] = bf1(W2[i]);
    } else if (i < 800 * 64 + 64 * 32) {
        int j = i - 800 * 64;
        int o = j >> 5, f = j & 31;
        r2T[o * 32 + f] = bf1(root2[f * 64 + o]);
    }
}

// ---------- K3c: per-edge basis precompute -> 32B records {b00,b01,b10,b11, s, ipack} ----------
__global__ __launch_bounds__(256) void k_basis(
    const int* __restrict__ r0, const int* __restrict__ r1, int E2,
    const float* __restrict__ pos2, const unsigned* __restrict__ scal,
    float* __restrict__ rec)
{
    int e = blockIdx.x * 256 + threadIdx.x;
    if (e >= E2) return;
    float denom = 2.0f * __uint_as_float(scal[1]);
    int d = r0[e], s = r1[e];          // true edge is (s -> d): cart = pos2[s] - pos2[d]
    float ax = (pos2[2 * s] - pos2[2 * d]) / denom + 0.5f;
    float ay = (pos2[2 * s + 1] - pos2[2 * d + 1]) / denom + 0.5f;
    int ix[4]; float bv[4];
    spline_sep(ax, ay, ix, bv);
    unsigned ip = (unsigned)ix[0] | ((unsigned)ix[1] << 8)
                | ((unsigned)ix[2] << 16) | ((unsigned)ix[3] << 24);
    float* rp = rec + (size_t)e * 8;
    *(float4*)rp = make_float4(bv[0], bv[1], bv[2], bv[3]);
    ((int*)rp)[4] = s;
    ((unsigned*)rp)[5] = ip;
}

// ---------- K4: conv2 FUSED scatter + MFMA GEMM + epilogue (no G buffer) ----------
// Block = 16 nodes, 256 threads. Phase 1: 16 subgroups x 16 lanes; lane owns a
// feature pair and keeps the FULL 25-tap accumulator in registers (50 VGPRs),
// built per edge via predicated separable selects — no LDS RMW chain, no atomics.
// One float2 dump per tap to LDS at the end (replaces zero-init). Phase 2:
// 4 waves x 16-col blocks, K=800 MFMA loop with A-frags read from LDS (b128 +
// RNE bf16 pack), fused epilogue (/deg, +x2@root2 via MFMA, +b2, elu, pool2 max).
__device__ __forceinline__ short8v ld_frag(const unsigned short* p) {
    short8v a;
    ((unsigned long long*)&a)[0] = *(const unsigned long long*)(p);        // k+0..3
    ((unsigned long long*)&a)[1] = *(const unsigned long long*)(p + 16);   // k+16..19
    return a;
}
__device__ __forceinline__ short8v pack_frag(float4 a, float4 b) {
    union { unsigned u[4]; short8v s; } r;
    r.u[0] = bfp2(a.x, a.y); r.u[1] = bfp2(a.z, a.w);
    r.u[2] = bfp2(b.x, b.y); r.u[3] = bfp2(b.z, b.w);
    return r.s;
}
__global__ __launch_bounds__(256) void k_conv2(
    const float* __restrict__ rec, const int* __restrict__ indptr2,
    const unsigned short* __restrict__ x2bf, const unsigned short* __restrict__ W2T,
    const unsigned short* __restrict__ r2T, const float* __restrict__ b2,
    const int* __restrict__ cluster2, unsigned* __restrict__ x3bits,
    const unsigned* __restrict__ scal, int N)
{
    __shared__ float accs[16 * ACCP];
    __shared__ float degl[16];
    int n2 = (int)scal[0] + 1;
    int nb = blockIdx.x * 16;
    if (nb >= n2) return;                 // block-uniform exit (before any barrier)
    int t = threadIdx.x;

    // ---- phase 1: per-subgroup register accumulation ----
    int g = t >> 4, f2 = (t & 15) << 1;   // subgroup (node-local), feature pair f2/f2+1
    int d = nb + g;
    int lo = 0, hi = 0;
    if (d < n2 && d < N) { lo = indptr2[d]; hi = indptr2[d + 1]; }
    if ((t & 15) == 0) degl[g] = (float)max(hi - lo, 1);

    float accx[25], accy[25];
#pragma unroll
    for (int k = 0; k < 25; ++k) { accx[k] = 0.f; accy[k] = 0.f; }

    for (int e = lo; e < hi; ++e) {
        const float* rp = rec + (size_t)e * 8;
        float4 bb = *(const float4*)rp;                 // b00,b01,b10,b11 (broadcast)
        int s = ((const int*)rp)[4];
        unsigned ip = ((const unsigned*)rp)[5];
        unsigned xv2 = *(const unsigned*)(x2bf + (size_t)s * 32 + f2);
        float xlo = __uint_as_float(xv2 << 16);
        float xhi = __uint_as_float(xv2 & 0xffff0000u);
        int i00 = ip & 255, i01 = (ip >> 8) & 255;
        int i10 = (ip >> 16) & 255, i11 = ip >> 24;
        float cx[5], cy[5];
#pragma unroll
        for (int i = 0; i < 5; ++i) {
            cx[i] = (i == i00 ? bb.x : 0.f) + (i == i01 ? bb.y : 0.f);
            cy[i] = (i == i10 ? bb.z : 0.f) + (i == i11 ? bb.w : 0.f);
        }
#pragma unroll
        for (int ky = 0; ky < 5; ++ky) {
            float mx = cy[ky] * xlo, my = cy[ky] * xhi;
#pragma unroll
            for (int kx = 0; kx < 5; ++kx) {
                accx[5 * ky + kx] += cx[kx] * mx;
                accy[5 * ky + kx] += cx[kx] * my;
            }
        }
    }
    // one-time dump to LDS (covers all 800 words/row -> no zero-init needed)
    float* acc = accs + g * ACCP + f2;
#pragma unroll
    for (int k = 0; k < 25; ++k)
        *(float2*)(acc + (k << 5)) = make_float2(accx[k], accy[k]);
    __syncthreads();

    // ---- phase 2: per-wave 16x16 col-block GEMM from LDS + fused epilogue ----
    int w = t >> 6, l = t & 63;
    int lg = l >> 4, lr = l & 15;
    int c0 = w * 16;
    const float* arow = accs + lr * ACCP;
    const unsigned short* pb = W2T + (size_t)(c0 + lr) * 800 + 4 * lg;

    f32x4 s4 = {0.f, 0.f, 0.f, 0.f};
    for (int kk = 0; kk < 800; kk += 32) {
        float4 a0 = *(const float4*)(arow + kk + 4 * lg);
        float4 a1 = *(const float4*)(arow + kk + 16 + 4 * lg);
        short8v af = pack_frag(a0, a1);
        short8v bf = ld_frag(pb + kk);
        s4 = __builtin_amdgcn_mfma_f32_16x16x32_bf16(af, bf, s4, 0, 0, 0);
    }

    int r0g = nb + 4 * lg;
#pragma unroll
    for (int i = 0; i < 4; ++i) {
        int gr = r0g + i;
        float invd = (gr < n2) ? 1.0f / degl[4 * lg + i] : 0.0f;
        s4[i] *= invd;
    }
    int ar2 = nb + lr; if (ar2 > N - 1) ar2 = N - 1;
    short8v a2f = ld_frag(x2bf + (size_t)ar2 * 32 + 4 * lg);
    s4 = __builtin_amdgcn_mfma_f32_16x16x32_bf16(
             a2f, ld_frag(r2T + (size_t)(c0 + lr) * 32 + 4 * lg), s4, 0, 0, 0);

    float bs = b2[c0 + lr];
#pragma unroll
    for (int i = 0; i < 4; ++i) {
        int gr = r0g + i;
        if (gr >= n2) continue;
        float h = s4[i] + bs;
        h = h > 0.f ? h : expm1f(h);
        atomicMax(&x3bits[(size_t)cluster2[gr] * 64 + c0 + lr], fkey(h));
    }
}

// ---------- K6: graph mean-pool numerators/denominators (LDS histogram) ----------
__global__ __launch_bounds__(256) void k_gsum(const unsigned* __restrict__ x3bits,
                                              const int* __restrict__ batch3,
                                              float* __restrict__ sbuf,
                                              unsigned* __restrict__ cbuf, int N)
{
    __shared__ float sl[NN_NG * 64];
    __shared__ unsigned clh[NN_NG];
    int t = threadIdx.x;
    for (int i = t; i < NN_NG * 64; i += 256) sl[i] = 0.f;
    if (t < NN_NG) clh[t] = 0u;
    __syncthreads();
    int o = t & 63, rsub = t >> 6;
    for (int i0 = blockIdx.x * 4; i0 < N; i0 += gridDim.x * 4) {
        int i = i0 + rsub;
        if (i < N) {
            int g = batch3[i];
            if (g < NN_NG) {   // dummy graph id NG is dropped
                float v = funkey(x3bits[(size_t)i * 64 + o]);
                atomicAdd(&sl[g * 64 + o], v);
                if (o == 0) atomicAdd(&clh[g], 1u);
            }
        }
    }
    __syncthreads();
    for (int i = t; i < NN_NG * 64; i += 256) atomicAdd(&sbuf[i], sl[i]);
    if (t < NN_NG) atomicAdd(&cbuf[t], clh[t]);
}

// ---------- K7: MLP head + log_softmax ----------
__global__ __launch_bounds__(128) void k_head(const float* __restrict__ sbuf,
                                              const unsigned* __restrict__ cbuf,
                                              const float* __restrict__ fc1w,
                                              const float* __restrict__ fc1b,
                                              const float* __restrict__ fc2w,
                                              const float* __restrict__ fc2b,
                                              float* __restrict__ out)
{
    __shared__ float xg[64], hl[NN_FH], ll[NN_NC];
    int g = blockIdx.x, t = threadIdx.x;
    if (t < 64) xg[t] = sbuf[g * 64 + t] / (float)max(cbuf[g], 1u);
    __syncthreads();
    float a = fc1b[t];
    for (int f = 0; f < 64; ++f) a += xg[f] * fc1w[f * NN_FH + t];
    hl[t] = a > 0.f ? a : expm1f(a);
    __syncthreads();
    if (t < NN_NC) {
        float l = fc2b[t];
        for (int h = 0; h < NN_FH; ++h) l += hl[h] * fc2w[h * NN_NC + t];
        ll[t] = l;
    }
    __syncthreads();
    if (t < NN_NC) {
        float m = ll[0];
        for (int j = 1; j < NN_NC; ++j) m = fmaxf(m, ll[j]);
        float sum = 0.f;
        for (int j = 0; j < NN_NC; ++j) sum += expf(ll[j] - m);
        out[g * NN_NC + t] = ll[t] - m - logf(sum);
    }
}

// ---------- launch ----------
extern "C" void kernel_launch(void* const* d_in, const int* in_sizes, int n_in,
                              void* d_out, int out_size, void* d_ws, size_t ws_size,
                              hipStream_t stream)
{
    const float* x        = (const float*)d_in[0];
    const float* pos      = (const float*)d_in[1];
    const float* eattr    = (const float*)d_in[2];
    const int*   ei       = (const int*)d_in[3];
    const int*   cluster1 = (const int*)d_in[4];
    const int*   ei2      = (const int*)d_in[5];
    const int*   cluster2 = (const int*)d_in[6];
    const int*   batch3   = (const int*)d_in[7];
    const float* W1    = (const float*)d_in[9];
    const float* root1 = (const float*)d_in[10];
    const float* b1    = (const float*)d_in[11];
    const float* W2    = (const float*)d_in[12];
    const float* root2 = (const float*)d_in[13];
    const float* b2    = (const float*)d_in[14];
    const float* fc1w  = (const float*)d_in[15];
    const float* fc1b  = (const float*)d_in[16];
    const float* fc2w  = (const float*)d_in[17];
    const float* fc2b  = (const float*)d_in[18];

    const int N  = in_sizes[0];        // x is [N,1]
    const int E  = in_sizes[3] / 2;
    const int E2 = in_sizes[5] / 2;

    char* base = (char*)d_ws;
    size_t off = 0;
    auto alloc = [&](size_t b) { size_t o = off; off += (b + 255) & ~(size_t)255; return o; };
    size_t o_x2b  = alloc((size_t)N * 32 * 4);   // x2bits (atomicMax target)
    size_t o_x3   = alloc((size_t)N * 64 * 4);   // x3bits
    size_t o_cnt1 = alloc((size_t)N * 4);
    size_t o_psum = alloc((size_t)N * 2 * 4);    // possum -> pos2 (in place)
    size_t o_ip1  = alloc((size_t)(N + 1) * 4);
    size_t o_ip2  = alloc((size_t)(N + 1) * 4);
    size_t o_s    = alloc((size_t)NN_NG * 64 * 4);
    size_t o_c    = alloc(64 * 4);
    size_t o_scal = alloc(256);                  // [0]=max cluster1, [1]=maxabs bits
    size_t fixed  = off;                         // memset covers [0, fixed)
    size_t o_x2bf = alloc((size_t)N * 32 * 2);   // x2 bf16 (fully written by fin1)
    size_t o_w2t  = alloc((size_t)64 * 800 * 2); // W2T bf16
    size_t o_r2t  = alloc((size_t)64 * 32 * 2);  // root2T bf16
    size_t o_rec  = alloc((size_t)E2 * 32);      // per-edge basis records
    (void)ws_size;

    unsigned* x2bits = (unsigned*)(base + o_x2b);
    unsigned* x3bits = (unsigned*)(base + o_x3);
    unsigned* cnt1   = (unsigned*)(base + o_cnt1);
    float*    possum = (float*)(base + o_psum);
    int*      ip1    = (int*)(base + o_ip1);
    int*      ip2    = (int*)(base + o_ip2);
    float*    sbuf   = (float*)(base + o_s);
    unsigned* cbuf   = (unsigned*)(base + o_c);
    unsigned* scal   = (unsigned*)(base + o_scal);
    unsigned short* x2bf = (unsigned short*)(base + o_x2bf);
    unsigned short* W2T  = (unsigned short*)(base + o_w2t);
    unsigned short* r2T  = (unsigned short*)(base + o_r2t);
    float*    rec    = (float*)(base + o_rec);

    hipMemsetAsync(d_ws, 0, fixed, stream);

    k_bounds<<<(N + 256) / 256, 256, 0, stream>>>(ei, E, ip1, N);
    k_bounds<<<(N + 256) / 256, 256, 0, stream>>>(ei2, E2, ip2, N);
    k_w2cvt<<<(800 * 64 + 64 * 32 + 255) / 256, 256, 0, stream>>>(W2, root2, W2T, r2T);

    k_conv1<<<(N + 127) / 128, 128, 0, stream>>>(x, pos, eattr, ei + E, ip1,
                                                 W1, root1, b1, cluster1,
                                                 x2bits, cnt1, possum, &scal[0], N);
    k_fin1<<<(N * 32 + 255) / 256, 256, 0, stream>>>(x2bits, cnt1, x2bf, possum, N);

    int mb = (E2 + 255) / 256;
    if (mb > 256) mb = 256;
    const float* pos2 = (const float*)(base + o_psum);
    k_maxabs<<<mb, 256, 0, stream>>>(ei2, ei2 + E2, E2, pos2, &scal[1]);
    k_basis<<<(E2 + 255) / 256, 256, 0, stream>>>(ei2, ei2 + E2, E2, pos2,
                                                  scal, rec);

    k_conv2<<<(N + 15) / 16, 256, 0, stream>>>(rec, ip2, x2bf, W2T, r2T, b2,
                                               cluster2, x3bits, scal, N);

    k_gsum<<<256, 256, 0, stream>>>(x3bits, batch3, sbuf, cbuf, N);
    k_head<<<NN_NG, 128, 0, stream>>>(sbuf, cbuf, fc1w, fc1b, fc2w, fc2b, (float*)d_out);
}

// Round 4
// 240.747 us; speedup vs baseline: 2.6525x; 1.0933x over previous
//
#include <hip/hip_runtime.h>
#include <math.h>

// GCN1: 2x SplineConv (deg-1 B-spline, KS=5, dim=2) + graclus max-pools + MLP head.
#define NN_F1 32
#define NN_F2 64
#define NN_FH 128
#define NN_NC 10
#define NN_NG 50
#define ACCPH 804  // padded A-row stride (u16/bf16 units): 800 used + 4 pad, 8B-aligned rows

typedef __attribute__((ext_vector_type(8))) short short8v;   // 8 bf16 = 4 VGPRs
typedef __attribute__((ext_vector_type(4))) float f32x4;

// ---------- helpers ----------
__device__ __forceinline__ unsigned fkey(float f) {
    unsigned u = __float_as_uint(f);
    return (u & 0x80000000u) ? ~u : (u | 0x80000000u);
}
__device__ __forceinline__ float funkey(unsigned k) {
    return (k & 0x80000000u) ? __uint_as_float(k & 0x7fffffffu) : __uint_as_float(~k);
}
// pack two floats -> two bf16 (RNE)
__device__ __forceinline__ unsigned bfp2(float a, float b) {
    unsigned ua = __float_as_uint(a), ub = __float_as_uint(b);
    ua += 0x7fffu + ((ua >> 16) & 1u);
    ub += 0x7fffu + ((ub >> 16) & 1u);
    return (ua >> 16) | (ub & 0xffff0000u);
}
__device__ __forceinline__ unsigned short bf1(float a) {
    unsigned u = __float_as_uint(a);
    u += 0x7fffu + ((u >> 16) & 1u);
    return (unsigned short)(u >> 16);
}

// degree-1 open B-spline, KS=5/dim, dim=2 — SEPARABLE form.
// ix = {i00,i01,i10,i11}, bv = {b00,b01,b10,b11}; flat tap = ix_x + 5*ix_y.
__device__ __forceinline__ void spline_sep(float ax, float ay, int ix[4], float bv[4]) {
    float v0 = ax * 4.0f, v1 = ay * 4.0f;
    float l0 = floorf(v0), l1 = floorf(v1);
    float f0 = v0 - l0, f1 = v1 - l1;
    int i0a = (int)l0, i1a = (int)l1;
    ix[0] = min(max(i0a, 0), 4);     ix[1] = min(max(i0a + 1, 0), 4);
    ix[2] = min(max(i1a, 0), 4);     ix[3] = min(max(i1a + 1, 0), 4);
    bv[0] = 1.0f - f0; bv[1] = f0; bv[2] = 1.0f - f1; bv[3] = f1;
}

// ---------- K0: CSR indptr via per-node parallel lower_bound ----------
__global__ __launch_bounds__(256) void k_bounds(const int* __restrict__ row, int E,
                                                int* __restrict__ indptr, int N)
{
    int d = blockIdx.x * 256 + threadIdx.x;
    if (d > N) return;
    if (d == N) { indptr[N] = E; return; }
    int l = 0, r = E;
    while (l < r) { int m = (l + r) >> 1; if (row[m] < d) l = m + 1; else r = m; }
    indptr[d] = l;
}

// ---------- K1: conv1, two-phase ----------
// Phase A: per-thread REGISTER accumulation (predicated separable selects),
// 2x unrolled edge loop for memory-level parallelism. One LDS dump at the end.
__device__ __forceinline__ void edge_accum1(float2 ea, float xv, float acc[25]) {
    int ix[4]; float bv[4];
    spline_sep(1.0f - ea.x, 1.0f - ea.y, ix, bv);
    float cx[5], cy[5];
#pragma unroll
    for (int i = 0; i < 5; ++i) {
        cx[i] = i == ix[0] ? bv[0] : (i == ix[1] ? bv[1] : 0.f);
        cy[i] = i == ix[2] ? bv[2] : (i == ix[3] ? bv[3] : 0.f);
    }
#pragma unroll
    for (int ky = 0; ky < 5; ++ky) {
        float m = cy[ky] * xv;
#pragma unroll
        for (int kx = 0; kx < 5; ++kx) acc[5 * ky + kx] += cx[kx] * m;
    }
}

__global__ __launch_bounds__(128) void k_conv1(
    const float* __restrict__ x, const float* __restrict__ pos,
    const float* __restrict__ eattr, const int* __restrict__ row1,
    const int* __restrict__ indptr,
    const float* __restrict__ W1, const float* __restrict__ root1,
    const float* __restrict__ b1, const int* __restrict__ cluster1,
    unsigned* __restrict__ x2bits, unsigned* __restrict__ cnt1,
    float* __restrict__ possum, unsigned* __restrict__ n2slot, int N)
{
    __shared__ float w1s[25 * NN_F1];
    __shared__ float r1s[NN_F1], b1s[NN_F1];
    __shared__ float g[128][25];          // stride 25 (odd) -> conflict-free
    __shared__ float invdeg[128], xds[128];
    __shared__ int   cls[128];
    __shared__ unsigned blkmax;
    int t = threadIdx.x;
    for (int i = t; i < 25 * NN_F1; i += 128) w1s[i] = W1[i];
    if (t < NN_F1) { r1s[t] = root1[t]; b1s[t] = b1[t]; }
    if (t == 0) blkmax = 0u;

    int d = blockIdx.x * 128 + t;
    float acc[25];
#pragma unroll
    for (int k = 0; k < 25; ++k) acc[k] = 0.f;

    if (d < N) {
        int lo = indptr[d], hi = indptr[d + 1];
        int e = lo;
        for (; e + 2 <= hi; e += 2) {
            int s0 = row1[e], s1 = row1[e + 1];
            float2 ea0 = ((const float2*)eattr)[e];
            float2 ea1 = ((const float2*)eattr)[e + 1];
            float xv0 = x[s0], xv1 = x[s1];
            edge_accum1(ea0, xv0, acc);
            edge_accum1(ea1, xv1, acc);
        }
        if (e < hi) {
            int s0 = row1[e];
            edge_accum1(((const float2*)eattr)[e], x[s0], acc);
        }
        invdeg[t] = 1.0f / (float)max(hi - lo, 1);
        xds[t] = x[d];
        int c = cluster1[d];
        cls[t] = c;
        atomicAdd(&cnt1[c], 1u);
        atomicAdd(&possum[2 * c], pos[2 * d]);
        atomicAdd(&possum[2 * c + 1], pos[2 * d + 1]);
        atomicMax(&blkmax, (unsigned)c);
    }
#pragma unroll
    for (int k = 0; k < 25; ++k) g[t][k] = acc[k];   // one-time dump
    __syncthreads();
    if (t == 0) atomicMax(n2slot, blkmax);

    // Phase B: 4 groups x 32 lanes; lane o owns output feature o.
    int grp = t >> 5, o = t & 31;
    float wreg[25];
#pragma unroll
    for (int k = 0; k < 25; ++k) wreg[k] = w1s[k * NN_F1 + o];
    float ro = r1s[o], bo = b1s[o];
    int nloc = min(128, N - blockIdx.x * 128);
    for (int i = grp; i < nloc; i += 4) {
        float a = 0.f;
#pragma unroll
        for (int k = 0; k < 25; ++k) a += g[i][k] * wreg[k];
        float h = a * invdeg[i] + xds[i] * ro + bo;
        h = h > 0.f ? h : expm1f(h);
        atomicMax(&x2bits[(size_t)cls[i] * NN_F1 + o], fkey(h));
    }
}

// ---------- K2: finalize x2 -> bf16 (zero empties), pos2 = possum/cnt ----------
__global__ __launch_bounds__(256) void k_fin1(const unsigned* __restrict__ x2b,
                                              const unsigned* __restrict__ cnt1,
                                              unsigned short* __restrict__ x2bf,
                                              float* __restrict__ possum, int N)
{
    int i = blockIdx.x * 256 + threadIdx.x;
    int n = i >> 5, o = i & 31;
    if (n >= N) return;
    unsigned cnt = cnt1[n];
    float v = cnt ? funkey(x2b[i]) : 0.0f;
    x2bf[i] = bf1(v);
    if (o < 2) {
        float p = possum[2 * n + o];
        possum[2 * n + o] = p / (float)max(cnt, 1u);
    }
}

// ---------- K3: global max|cart| over pooled edges (block-reduced, 1 atomic/block) ----------
__global__ __launch_bounds__(256) void k_maxabs(const int* __restrict__ r0,
                                                const int* __restrict__ r1, int E2,
                                                const float* __restrict__ pos2,
                                                unsigned* __restrict__ maxbits)
{
    __shared__ float wmax[4];
    float m = 0.f;
    for (int e = blockIdx.x * 256 + threadIdx.x; e < E2; e += gridDim.x * 256) {
        int a = r0[e], b = r1[e];
        float cx = pos2[2 * a] - pos2[2 * b];
        float cy = pos2[2 * a + 1] - pos2[2 * b + 1];
        m = fmaxf(m, fmaxf(fabsf(cx), fabsf(cy)));
    }
    for (int off = 32; off; off >>= 1) m = fmaxf(m, __shfl_down(m, off));
    if ((threadIdx.x & 63) == 0) wmax[threadIdx.x >> 6] = m;
    __syncthreads();
    if (threadIdx.x == 0) {
        m = fmaxf(fmaxf(wmax[0], wmax[1]), fmaxf(wmax[2], wmax[3]));
        atomicMax(maxbits, __float_as_uint(m));   // all values >= 0: bit-compare ok
    }
}

// ---------- K3b: W2 -> W2T bf16 [64][800]; root2 -> r2T bf16 [64][32] ----------
__global__ __launch_bounds__(256) void k_w2cvt(const float* __restrict__ W2,
                                               const float* __restrict__ root2,
                                               unsigned short* __restrict__ W2T,
                                               unsigned short* __restrict__ r2T)
{
    int i = blockIdx.x * 256 + threadIdx.x;
    if (i < 800 * 64) {
        int k = i >> 6, n = i & 63;
        W2T[n * 800 + k] = bf1(W2[i]);
    } else if (i < 800 * 64 + 64 * 32) {
        int j = i - 800 * 64;
        int o = j >> 5, f = j & 31;
        r2T[o * 32 + f] = bf1(root2[f * 64 + o]);
    }
}

// ---------- K3c: per-edge basis precompute -> 32B records {b00,b01,b10,b11, s, ipack} ----------
__global__ __launch_bounds__(256) void k_basis(
    const int* __restrict__ r0, const int* __restrict__ r1, int E2,
    const float* __restrict__ pos2, const unsigned* __restrict__ scal,
    float* __restrict__ rec)
{
    int e = blockIdx.x * 256 + threadIdx.x;
    if (e >= E2) return;
    float denom = 2.0f * __uint_as_float(scal[1]);
    int d = r0[e], s = r1[e];          // true edge is (s -> d): cart = pos2[s] - pos2[d]
    float ax = (pos2[2 * s] - pos2[2 * d]) / denom + 0.5f;
    float ay = (pos2[2 * s + 1] - pos2[2 * d + 1]) / denom + 0.5f;
    int ix[4]; float bv[4];
    spline_sep(ax, ay, ix, bv);
    unsigned ip = (unsigned)ix[0] | ((unsigned)ix[1] << 8)
                | ((unsigned)ix[2] << 16) | ((unsigned)ix[3] << 24);
    float* rp = rec + (size_t)e * 8;
    *(float4*)rp = make_float4(bv[0], bv[1], bv[2], bv[3]);
    ((int*)rp)[4] = s;
    ((unsigned*)rp)[5] = ip;
}

// ---------- K4: conv2 FUSED scatter + MFMA GEMM + epilogue ----------
// Block = 16 nodes, 256 threads. Phase 1: 16 subgroups x 16 lanes; lane owns a
// feature pair, keeps the full 25-tap accumulator in registers (50 VGPRs);
// 2x-unrolled edge loop (batched loads -> MLP). Dump is RNE-bf16 (bit-identical
// to the old pack_frag rounding) -> LDS is HALF the size (25.9 KB: ~5-6 blk/CU)
// and phase 2 reads A-frags directly with ld_frag (no pack).
__device__ __forceinline__ short8v ld_frag(const unsigned short* p) {
    short8v a;
    ((unsigned long long*)&a)[0] = *(const unsigned long long*)(p);        // k+0..3
    ((unsigned long long*)&a)[1] = *(const unsigned long long*)(p + 16);   // k+16..19
    return a;
}
__device__ __forceinline__ void edge_accum2(float4 bb, unsigned ip, unsigned xv2,
                                            float accx[25], float accy[25]) {
    float xlo = __uint_as_float(xv2 << 16);
    float xhi = __uint_as_float(xv2 & 0xffff0000u);
    int i00 = ip & 255, i01 = (ip >> 8) & 255;
    int i10 = (ip >> 16) & 255, i11 = ip >> 24;
    float cx[5], cy[5];
#pragma unroll
    for (int i = 0; i < 5; ++i) {
        cx[i] = i == i00 ? bb.x : (i == i01 ? bb.y : 0.f);
        cy[i] = i == i10 ? bb.z : (i == i11 ? bb.w : 0.f);
    }
#pragma unroll
    for (int ky = 0; ky < 5; ++ky) {
        float mx = cy[ky] * xlo, my = cy[ky] * xhi;
#pragma unroll
        for (int kx = 0; kx < 5; ++kx) {
            accx[5 * ky + kx] += cx[kx] * mx;
            accy[5 * ky + kx] += cx[kx] * my;
        }
    }
}
__global__ __launch_bounds__(256) void k_conv2(
    const float* __restrict__ rec, const int* __restrict__ indptr2,
    const unsigned short* __restrict__ x2bf, const unsigned short* __restrict__ W2T,
    const unsigned short* __restrict__ r2T, const float* __restrict__ b2,
    const int* __restrict__ cluster2, unsigned* __restrict__ x3bits,
    const unsigned* __restrict__ scal, int N)
{
    __shared__ unsigned short accs[16 * ACCPH];   // bf16 A-tile [16 rows][800+4]
    __shared__ float degl[16];
    int n2 = (int)scal[0] + 1;
    int nb = blockIdx.x * 16;
    if (nb >= n2) return;                 // block-uniform exit (before any barrier)
    int t = threadIdx.x;

    // ---- phase 1: per-subgroup register accumulation, 2x unrolled ----
    int g = t >> 4, f2 = (t & 15) << 1;   // subgroup (node-local), feature pair f2/f2+1
    int d = nb + g;
    int lo = 0, hi = 0;
    if (d < n2 && d < N) { lo = indptr2[d]; hi = indptr2[d + 1]; }
    if ((t & 15) == 0) degl[g] = (float)max(hi - lo, 1);

    float accx[25], accy[25];
#pragma unroll
    for (int k = 0; k < 25; ++k) { accx[k] = 0.f; accy[k] = 0.f; }

    int e = lo;
    for (; e + 2 <= hi; e += 2) {
        const float* rp0 = rec + (size_t)e * 8;
        const float* rp1 = rp0 + 8;
        float4 bb0 = *(const float4*)rp0;
        int s0 = ((const int*)rp0)[4];
        unsigned ip0 = ((const unsigned*)rp0)[5];
        float4 bb1 = *(const float4*)rp1;
        int s1 = ((const int*)rp1)[4];
        unsigned ip1 = ((const unsigned*)rp1)[5];
        unsigned xa = *(const unsigned*)(x2bf + (size_t)s0 * 32 + f2);
        unsigned xb = *(const unsigned*)(x2bf + (size_t)s1 * 32 + f2);
        edge_accum2(bb0, ip0, xa, accx, accy);
        edge_accum2(bb1, ip1, xb, accx, accy);
    }
    if (e < hi) {
        const float* rp0 = rec + (size_t)e * 8;
        float4 bb0 = *(const float4*)rp0;
        int s0 = ((const int*)rp0)[4];
        unsigned ip0 = ((const unsigned*)rp0)[5];
        unsigned xa = *(const unsigned*)(x2bf + (size_t)s0 * 32 + f2);
        edge_accum2(bb0, ip0, xa, accx, accy);
    }
    // one-time bf16 dump (covers all 800 used u16/row -> no zero-init needed)
    unsigned short* arow_w = accs + g * ACCPH + f2;
#pragma unroll
    for (int k = 0; k < 25; ++k)
        *(unsigned*)(arow_w + (k << 5)) = bfp2(accx[k], accy[k]);
    __syncthreads();

    // ---- phase 2: per-wave 16x16 col-block GEMM (A from bf16 LDS) + epilogue ----
    int w = t >> 6, l = t & 63;
    int lg = l >> 4, lr = l & 15;
    int c0 = w * 16;
    const unsigned short* pa = accs + lr * ACCPH + 4 * lg;
    const unsigned short* pb = W2T + (size_t)(c0 + lr) * 800 + 4 * lg;

    f32x4 s4 = {0.f, 0.f, 0.f, 0.f};
    for (int kk = 0; kk < 800; kk += 32) {
        short8v af = ld_frag(pa + kk);
        short8v bf = ld_frag(pb + kk);
        s4 = __builtin_amdgcn_mfma_f32_16x16x32_bf16(af, bf, s4, 0, 0, 0);
    }

    int r0g = nb + 4 * lg;
#pragma unroll
    for (int i = 0; i < 4; ++i) {
        int gr = r0g + i;
        float invd = (gr < n2) ? 1.0f / degl[4 * lg + i] : 0.0f;
        s4[i] *= invd;
    }
    int ar2 = nb + lr; if (ar2 > N - 1) ar2 = N - 1;
    short8v a2f = ld_frag(x2bf + (size_t)ar2 * 32 + 4 * lg);
    s4 = __builtin_amdgcn_mfma_f32_16x16x32_bf16(
             a2f, ld_frag(r2T + (size_t)(c0 + lr) * 32 + 4 * lg), s4, 0, 0, 0);

    float bs = b2[c0 + lr];
#pragma unroll
    for (int i = 0; i < 4; ++i) {
        int gr = r0g + i;
        if (gr >= n2) continue;
        float h = s4[i] + bs;
        h = h > 0.f ? h : expm1f(h);
        atomicMax(&x3bits[(size_t)cluster2[gr] * 64 + c0 + lr], fkey(h));
    }
}

// ---------- K6: graph mean-pool numerators/denominators (LDS histogram) ----------
__global__ __launch_bounds__(256) void k_gsum(const unsigned* __restrict__ x3bits,
                                              const int* __restrict__ batch3,
                                              float* __restrict__ sbuf,
                                              unsigned* __restrict__ cbuf, int N)
{
    __shared__ float sl[NN_NG * 64];
    __shared__ unsigned clh[NN_NG];
    int t = threadIdx.x;
    for (int i = t; i < NN_NG * 64; i += 256) sl[i] = 0.f;
    if (t < NN_NG) clh[t] = 0u;
    __syncthreads();
    int o = t & 63, rsub = t >> 6;
    for (int i0 = blockIdx.x * 4; i0 < N; i0 += gridDim.x * 4) {
        int i = i0 + rsub;
        if (i < N) {
            int g = batch3[i];
            if (g < NN_NG) {   // dummy graph id NG is dropped
                float v = funkey(x3bits[(size_t)i * 64 + o]);
                atomicAdd(&sl[g * 64 + o], v);
                if (o == 0) atomicAdd(&clh[g], 1u);
            }
        }
    }
    __syncthreads();
    for (int i = t; i < NN_NG * 64; i += 256) atomicAdd(&sbuf[i], sl[i]);
    if (t < NN_NG) atomicAdd(&cbuf[t], clh[t]);
}

// ---------- K7: MLP head + log_softmax ----------
__global__ __launch_bounds__(128) void k_head(const float* __restrict__ sbuf,
                                              const unsigned* __restrict__ cbuf,
                                              const float* __restrict__ fc1w,
                                              const float* __restrict__ fc1b,
                                              const float* __restrict__ fc2w,
                                              const float* __restrict__ fc2b,
                                              float* __restrict__ out)
{
    __shared__ float xg[64], hl[NN_FH], ll[NN_NC];
    int g = blockIdx.x, t = threadIdx.x;
    if (t < 64) xg[t] = sbuf[g * 64 + t] / (float)max(cbuf[g], 1u);
    __syncthreads();
    float a = fc1b[t];
    for (int f = 0; f < 64; ++f) a += xg[f] * fc1w[f * NN_FH + t];
    hl[t] = a > 0.f ? a : expm1f(a);
    __syncthreads();
    if (t < NN_NC) {
        float l = fc2b[t];
        for (int h = 0; h < NN_FH; ++h) l += hl[h] * fc2w[h * NN_NC + t];
        ll[t] = l;
    }
    __syncthreads();
    if (t < NN_NC) {
        float m = ll[0];
        for (int j = 1; j < NN_NC; ++j) m = fmaxf(m, ll[j]);
        float sum = 0.f;
        for (int j = 0; j < NN_NC; ++j) sum += expf(ll[j] - m);
        out[g * NN_NC + t] = ll[t] - m - logf(sum);
    }
}

// ---------- launch ----------
extern "C" void kernel_launch(void* const* d_in, const int* in_sizes, int n_in,
                              void* d_out, int out_size, void* d_ws, size_t ws_size,
                              hipStream_t stream)
{
    const float* x        = (const float*)d_in[0];
    const float* pos      = (const float*)d_in[1];
    const float* eattr    = (const float*)d_in[2];
    const int*   ei       = (const int*)d_in[3];
    const int*   cluster1 = (const int*)d_in[4];
    const int*   ei2      = (const int*)d_in[5];
    const int*   cluster2 = (const int*)d_in[6];
    const int*   batch3   = (const int*)d_in[7];
    const float* W1    = (const float*)d_in[9];
    const float* root1 = (const float*)d_in[10];
    const float* b1    = (const float*)d_in[11];
    const float* W2    = (const float*)d_in[12];
    const float* root2 = (const float*)d_in[13];
    const float* b2    = (const float*)d_in[14];
    const float* fc1w  = (const float*)d_in[15];
    const float* fc1b  = (const float*)d_in[16];
    const float* fc2w  = (const float*)d_in[17];
    const float* fc2b  = (const float*)d_in[18];

    const int N  = in_sizes[0];        // x is [N,1]
    const int E  = in_sizes[3] / 2;
    const int E2 = in_sizes[5] / 2;

    char* base = (char*)d_ws;
    size_t off = 0;
    auto alloc = [&](size_t b) { size_t o = off; off += (b + 255) & ~(size_t)255; return o; };
    size_t o_x2b  = alloc((size_t)N * 32 * 4);   // x2bits (atomicMax target)
    size_t o_x3   = alloc((size_t)N * 64 * 4);   // x3bits
    size_t o_cnt1 = alloc((size_t)N * 4);
    size_t o_psum = alloc((size_t)N * 2 * 4);    // possum -> pos2 (in place)
    size_t o_ip1  = alloc((size_t)(N + 1) * 4);
    size_t o_ip2  = alloc((size_t)(N + 1) * 4);
    size_t o_s    = alloc((size_t)NN_NG * 64 * 4);
    size_t o_c    = alloc(64 * 4);
    size_t o_scal = alloc(256);                  // [0]=max cluster1, [1]=maxabs bits
    size_t fixed  = off;                         // memset covers [0, fixed)
    size_t o_x2bf = alloc((size_t)N * 32 * 2);   // x2 bf16 (fully written by fin1)
    size_t o_w2t  = alloc((size_t)64 * 800 * 2); // W2T bf16
    size_t o_r2t  = alloc((size_t)64 * 32 * 2);  // root2T bf16
    size_t o_rec  = alloc((size_t)E2 * 32);      // per-edge basis records
    (void)ws_size;

    unsigned* x2bits = (unsigned*)(base + o_x2b);
    unsigned* x3bits = (unsigned*)(base + o_x3);
    unsigned* cnt1   = (unsigned*)(base + o_cnt1);
    float*    possum = (float*)(base + o_psum);
    int*      ip1    = (int*)(base + o_ip1);
    int*      ip2    = (int*)(base + o_ip2);
    float*    sbuf   = (float*)(base + o_s);
    unsigned* cbuf   = (unsigned*)(base + o_c);
    unsigned* scal   = (unsigned*)(base + o_scal);
    unsigned short* x2bf = (unsigned short*)(base + o_x2bf);
    unsigned short* W2T  = (unsigned short*)(base + o_w2t);
    unsigned short* r2T  = (unsigned short*)(base + o_r2t);
    float*    rec    = (float*)(base + o_rec);

    hipMemsetAsync(d_ws, 0, fixed, stream);

    k_bounds<<<(N + 256) / 256, 256, 0, stream>>>(ei, E, ip1, N);
    k_bounds<<<(N + 256) / 256, 256, 0, stream>>>(ei2, E2, ip2, N);
    k_w2cvt<<<(800 * 64 + 64 * 32 + 255) / 256, 256, 0, stream>>>(W2, root2, W2T, r2T);

    k_conv1<<<(N + 127) / 128, 128, 0, stream>>>(x, pos, eattr, ei + E, ip1,
                                                 W1, root1, b1, cluster1,
                                                 x2bits, cnt1, possum, &scal[0], N);
    k_fin1<<<(N * 32 + 255) / 256, 256, 0, stream>>>(x2bits, cnt1, x2bf, possum, N);

    int mb = (E2 + 255) / 256;
    if (mb > 256) mb = 256;
    const float* pos2 = (const float*)(base + o_psum);
    k_maxabs<<<mb, 256, 0, stream>>>(ei2, ei2 + E2, E2, pos2, &scal[1]);
    k_basis<<<(E2 + 255) / 256, 256, 0, stream>>>(ei2, ei2 + E2, E2, pos2,
                                                  scal, rec);

    k_conv2<<<(N + 15) / 16, 256, 0, stream>>>(rec, ip2, x2bf, W2T, r2T, b2,
                                               cluster2, x3bits, scal, N);

    k_gsum<<<256, 256, 0, stream>>>(x3bits, batch3, sbuf, cbuf, N);
    k_head<<<NN_NG, 128, 0, stream>>>(sbuf, cbuf, fc1w, fc1b, fc2w, fc2b, (float*)d_out);
}